// Round 5
// baseline (232.646 us; speedup 1.0000x reference)
//
#include <hip/hip_runtime.h>
#include <hip/hip_fp16.h>
#include <cmath>

#define B_SZ 2048
#define D_IN 512
#define U_N  512
#define FD   1024   // D_IN + U_N
#define NRU  4096   // U_N * M_B
#define NRU2 8192   // combined r+u output cols

typedef _Float16 f16x8 __attribute__((ext_vector_type(8)));
typedef float    f32x4 __attribute__((ext_vector_type(4)));

typedef const __attribute__((address_space(1))) void glb_cv;
typedef __attribute__((address_space(3))) void lds_v;

#define TAB_INIT {0.0f, 1.15129254649702f, 2.30258509299405f, \
                  3.45387763949107f, 4.60517018598809f, 5.75646273248511f, \
                  6.90775527898214f, 8.05904782547916f}

// ---------------------------------------------------------------------------
// P1: h = sum_m state[b,u,m]; fused = [f16(inputs), f16(h)]; reset[:,0:512]=f16(inputs)
// ---------------------------------------------------------------------------
__global__ __launch_bounds__(256) void prep_kernel(
    const float* __restrict__ inputs, const float* __restrict__ state,
    __half* __restrict__ fused, __half* __restrict__ reset)
{
    const int b = blockIdx.x;
    const int t = threadIdx.x;

    const float2 iv = *(const float2*)(inputs + (size_t)b * D_IN + t * 2);
    __half2 hv;
    hv.x = __float2half(iv.x);
    hv.y = __float2half(iv.y);
    *(__half2*)(fused + (size_t)b * FD + t * 2) = hv;
    *(__half2*)(reset + (size_t)b * FD + t * 2) = hv;

    const float4* sp = (const float4*)(state + (size_t)b * NRU + t * 16);
    float4 x0 = sp[0], x1 = sp[1], x2 = sp[2], x3 = sp[3];
    float s0 = (x0.x + x0.y) + (x0.z + x0.w) + (x1.x + x1.y) + (x1.z + x1.w);
    float s1 = (x2.x + x2.y) + (x2.z + x2.w) + (x3.x + x3.y) + (x3.z + x3.w);
    __half2 h2;
    h2.x = __float2half(s0);
    h2.y = __float2half(s1);
    *(__half2*)(fused + (size_t)b * FD + D_IN + t * 2) = h2;
}

// ---------------------------------------------------------------------------
// P2 (merged): transpose-convert W_r, W_u, W_d in one launch.
// ---------------------------------------------------------------------------
__global__ __launch_bounds__(256) void convT3_kernel(
    const float* __restrict__ W_r, const float* __restrict__ W_u,
    const float* __restrict__ W_d, __half* __restrict__ WruT,
    __half* __restrict__ WdT)
{
    __shared__ float tile[32][33];
    const int bx = blockIdx.x;
    const float* W;
    __half* Wt;
    int N, nt;
    if (bx < 128)      { W = W_r; Wt = WruT;                    N = NRU; nt = bx * 32; }
    else if (bx < 256) { W = W_u; Wt = WruT + (size_t)NRU * FD; N = NRU; nt = (bx - 128) * 32; }
    else               { W = W_d; Wt = WdT;                     N = U_N; nt = (bx - 256) * 32; }

    const int kt = blockIdx.y * 32;
    const int t  = threadIdx.x;
    const int c  = t & 31;
    const int r4 = t >> 5;

#pragma unroll
    for (int i = 0; i < 4; i++) {
        int r = r4 + i * 8;
        tile[r][c] = W[(size_t)(kt + r) * N + nt + c];
    }
    __syncthreads();
#pragma unroll
    for (int i = 0; i < 4; i++) {
        int rr = r4 + i * 8;
        Wt[(size_t)(nt + rr) * FD + kt + c] = __float2half(tile[c][rr]);
    }
}

// ---------------------------------------------------------------------------
// Big GEMM: 256x256 tile, 4-phase / 2-K-tile schedule, 1024 threads = 16
// waves (round-5 change: TLP 2 -> 4 waves/SIMD).
//
// Round-4 post-mortem: dropping barrier1 was NEUTRAL (MfmaUtil ~28%).
// Measured time ~= LDS-pipe + MFMA-pipe SERIAL SUM: per K-tile per CU,
// LDS ~2304 cyc + MFMA ~2483 cyc. With 8 waves (2/SIMD) both waves of a
// SIMD move through phases in near-lockstep, so the pipes alternate.
// Fix: 16 waves (4M x 4N, per-wave output 64x64), 4 waves/SIMD -- enough
// TLP for lagging waves' ds_reads to overlap leading waves' MFMA.
// Cost: per-CU LDS reads rise 192->256 b128/K-tile (less per-wave reuse);
// LDS becomes the nominal pipe (~3072 cyc/tile); floor ~20 us main loop.
//
// Schedule (identical protocol to round 3/4, stage group now 2 loads):
//   P1: read bufE B-all(8) + A-h0(4), MFMA Q0(16); stage bufO.A(t1) [2]
//   P2: read bufE A-h1(4),            MFMA Q1(16); stage bufE.B(t2) [2]; WAITV(2)
//   P3: read bufO B-all + A-h0,       MFMA Q0;     stage bufE.A(t2) [2]
//   P4: read bufO A-h1,               MFMA Q1;     stage bufO.B(t3) [2]; WAITV(2)
// FIFO induction: after each end-even-phase WAITV(2), exactly the newest
// 2-load group remains in flight; every READ target retired >=1 barrier
// earlier; every STAGE overwrites a slot last read before the preceding
// barrier (P2 stages bufE.B which P2 does NOT read -- only A-h1).
// Tail stages clamp tile idx (&15): inert, in-bounds; drained before the
// epilogue reuses LDS. acc[mi][ni]: rows mi*64 + wm*16, cols wn*64 + ni*16.
// Register budget: acc 64 + bf 32 + af 16 + addr ~= 125 <= 128 (mandatory
// for 16-wave blocks; __launch_bounds__(1024,4)).
// ---------------------------------------------------------------------------
__global__ __launch_bounds__(1024, 4) void gemm_big(
    const __half* __restrict__ A, const __half* __restrict__ Bt,
    const float* __restrict__ b_r, const float* __restrict__ b_u,
    const float* __restrict__ state, __half* __restrict__ resetw,
    __half* __restrict__ skibuf)
{
    __shared__ __align__(16) char smem[131072];
    __half* SAh = (__half*)smem;

    const int t    = threadIdx.x;
    const int m0   = blockIdx.y << 8;
    const int n0   = blockIdx.x << 8;
    const int lane = t & 63;
    const int w    = t >> 6;          // 0..15
    const int wn   = w & 3;           // n-wave (64-col span)
    const int wm   = w >> 2;          // m-wave (16-row offset within each 64-row span)
    const int m16  = lane & 15;
    const int quad = lane >> 4;
    const int g0   = (quad ^ (m16 & 7)) << 3;        // ks=0 granule (f16 units)
    const int g1   = ((quad + 4) ^ (m16 & 7)) << 3;  // ks=1 granule
    const int t8   = t << 3;                          // per-thread LDS dst (f16)
    const int trow = t >> 3;                          // 0..127
    const int gcol = ((t & 7) ^ (trow & 7)) << 3;    // pre-swizzled global granule

    const __half* gA = A  + (size_t)(m0 + trow) * FD + gcol;
    const __half* gB = Bt + (size_t)(n0 + trow) * FD + gcol;

    f32x4 acc[4][4];
#pragma unroll
    for (int a1 = 0; a1 < 4; a1++)
#pragma unroll
        for (int a2 = 0; a2 < 4; a2++)
            acc[a1][a2] = (f32x4){0.f, 0.f, 0.f, 0.f};

#define BARRIER() __builtin_amdgcn_s_barrier()
#define PRIO1 __builtin_amdgcn_s_setprio(1)
#define PRIO0 __builtin_amdgcn_s_setprio(0)
#define WAITV(n) do { asm volatile("s_waitcnt vmcnt(" #n ")" ::: "memory"); \
                      __builtin_amdgcn_sched_barrier(0); } while (0)
#define WAITL() do { asm volatile("s_waitcnt lgkmcnt(0)" ::: "memory"); \
                     __builtin_amdgcn_sched_barrier(0); } while (0)

// one chunk (128 rows x 64 halfs = 16KB) = 1 x global_load_lds width 16
#define STAGE_A(buf, h, tt) do { \
        const __half* _s = gA + (size_t)((h) * 128) * FD + (tt) * 64; \
        __half* _d = SAh + (buf) * 32768 + (h) * 8192 + t8; \
        __builtin_amdgcn_global_load_lds((glb_cv*)_s, (lds_v*)_d, 16, 0, 0); } while (0)
#define STAGE_B(buf, h, tt) do { \
        const __half* _s = gB + (size_t)((h) * 128) * FD + (tt) * 64; \
        __half* _d = SAh + (buf) * 32768 + 16384 + (h) * 8192 + t8; \
        __builtin_amdgcn_global_load_lds((glb_cv*)_s, (lds_v*)_d, 16, 0, 0); } while (0)

// A frags: rows (mh*2+mi2)*64 + wm*16 + m16  (Q(mh) -> rows of half mh)
#define READ_A(c, mh) do { _Pragma("unroll") \
    for (int mi2 = 0; mi2 < 2; mi2++) { \
        const __half* _ap = SAh + (c) * 32768 + \
            (((((mh) * 2 + mi2) * 64) + wm * 16 + m16) << 6); \
        af[mi2][0] = *(const f16x8*)(_ap + g0); \
        af[mi2][1] = *(const f16x8*)(_ap + g1); } } while (0)
// B frags: rows wn*64 + ni2*16 + m16
#define READ_B_ALL(c) do { _Pragma("unroll") \
    for (int ni2 = 0; ni2 < 4; ni2++) { \
        const __half* _bp = SAh + (c) * 32768 + 16384 + \
            ((wn * 64 + ni2 * 16 + m16) << 6); \
        bf[ni2][0] = *(const f16x8*)(_bp + g0); \
        bf[ni2][1] = *(const f16x8*)(_bp + g1); } } while (0)

// all ks0 MFMAs first, then all ks1 (dep distance 8)
#define MFMA_Q(MH) do { _Pragma("unroll") \
    for (int ks = 0; ks < 2; ks++) { _Pragma("unroll") \
        for (int mi2 = 0; mi2 < 2; mi2++) { _Pragma("unroll") \
            for (int ni2 = 0; ni2 < 4; ni2++) { \
                acc[(MH)*2+mi2][ni2] = __builtin_amdgcn_mfma_f32_16x16x32_f16( \
                    af[mi2][ks], bf[ni2][ks], acc[(MH)*2+mi2][ni2], 0, 0, 0); } } } } while (0)

    // ---- prologue: bufE.B(t0), bufE.A(t0), bufO.B(t1); retire bufE groups,
    // keep bufO.B (2 loads) in flight. ----
    STAGE_B(0, 0, 0); STAGE_B(0, 1, 0);
    STAGE_A(0, 0, 0); STAGE_A(0, 1, 0);
    STAGE_B(1, 0, 1); STAGE_B(1, 1, 1);
    WAITV(2);
    BARRIER();

#pragma unroll 1
    for (int i = 0; i < 8; i++) {
        const int t1 = (2 * i + 1) & 15, t2 = (2 * i + 2) & 15, t3 = (2 * i + 3) & 15;
        f16x8 bf[4][2];
        // ---- P1: tile 2i (bufE) quadrant 0 ----
        {
            f16x8 af[2][2];
            READ_B_ALL(0); READ_A(0, 0);
            STAGE_A(1, 0, t1); STAGE_A(1, 1, t1);
            WAITL(); PRIO1; MFMA_Q(0); PRIO0; BARRIER();
        }
        // ---- P2: tile 2i quadrant 1 (B live in regs) ----
        {
            f16x8 af[2][2];
            READ_A(0, 1);
            STAGE_B(0, 0, t2); STAGE_B(0, 1, t2);
            WAITL(); PRIO1; MFMA_Q(1); PRIO0; WAITV(2); BARRIER();
        }
        // ---- P3: tile 2i+1 (bufO) quadrant 0 ----
        {
            f16x8 af[2][2];
            READ_B_ALL(1); READ_A(1, 0);
            STAGE_A(0, 0, t2); STAGE_A(0, 1, t2);
            WAITL(); PRIO1; MFMA_Q(0); PRIO0; BARRIER();
        }
        // ---- P4: tile 2i+1 quadrant 1 ----
        {
            f16x8 af[2][2];
            READ_A(1, 1);
            STAGE_B(1, 0, t3); STAGE_B(1, 1, t3);
            WAITL(); PRIO1; MFMA_Q(1); PRIO0; WAITV(2); BARRIER();
        }
    }

    WAITV(0);          // drain tail prefetches before LDS reuse
    __syncthreads();

#undef BARRIER
#undef PRIO1
#undef PRIO0
#undef WAITV
#undef WAITL
#undef STAGE_A
#undef STAGE_B
#undef READ_A
#undef READ_B_ALL
#undef MFMA_Q

    // -------- fused CTGRU gate epilogue, 1024 threads --------
    // acc[mi][ni][r]: row = mi*64 + wm*16 + quad*4 + r (block-local),
    //                 global col = n0 + wn*64 + ni*16 + m16.
    // ebuf col x = wn*16 + m16  <->  global col (x>>4)*64 + ni*16 + (x&15).
    float*  ebuf = (float*)smem;                     // [256][68]
    __half* qbuf = (__half*)(smem + 256 * 68 * 4);   // [256][8]
    const bool is_r = (n0 < NRU);
    const float* bp = is_r ? b_r : b_u;
    const int n0r = is_r ? n0 : n0 - NRU;
    const float TAB[8] = TAB_INIT;

    for (int ni = 0; ni < 4; ni++) {
        const float bv = bp[n0r + wn * 64 + ni * 16 + m16];
#pragma unroll
        for (int mi = 0; mi < 4; mi++)
#pragma unroll
            for (int r = 0; r < 4; r++)
                ebuf[(mi * 64 + wm * 16 + quad * 4 + r) * 68 + wn * 16 + m16] =
                    acc[mi][ni][r] + bv;
        __syncthreads();

#pragma unroll
        for (int p = 0; p < 2; p++) {
            const int item = p * 1024 + t;       // 0..2047 = 256 rows x 8 groups
            const int row = item >> 3, g = item & 7;
            const int b = m0 + row;
            const float* rp = ebuf + row * 68 + g * 8;
            float v[8];
            *(float4*)&v[0] = *(const float4*)rp;
            *(float4*)&v[4] = *(const float4*)(rp + 4);

            float e[8], sum = 0.f;
#pragma unroll
            for (int i2 = 0; i2 < 8; i2++) {
                float d = v[i2] - TAB[i2];
                e[i2] = __expf(-d * d);
                sum += e[i2];
            }
            // global flat (u*8) col for this 8-group:
            const int colr = n0r + (g >> 1) * 64 + ni * 16 + (g & 1) * 8;
            if (is_r) {
                const float4 h0 = *(const float4*)(state + (size_t)b * NRU + colr);
                const float4 h1 = *(const float4*)(state + (size_t)b * NRU + colr + 4);
                const float hv[8] = {h0.x, h0.y, h0.z, h0.w, h1.x, h1.y, h1.z, h1.w};
                float qn = 0.f;
#pragma unroll
                for (int i2 = 0; i2 < 8; i2++) qn += e[i2] * hv[i2];
                qbuf[row * 8 + g] = __float2half(qn / sum);
            } else {
                const float inv = 1.0f / sum;
                __half2 o[4];
#pragma unroll
                for (int i2 = 0; i2 < 4; i2++) {
                    o[i2].x = __float2half(e[2 * i2] * inv);
                    o[i2].y = __float2half(e[2 * i2 + 1] * inv);
                }
                *(uint4*)(skibuf + (size_t)b * NRU + colr) = *(uint4*)o;
            }
        }
        __syncthreads();
        if (is_r) {
            // qbuf[row*8 + g] holds q for u = (g>>1)*8 + ni*2 + (g&1).
            // Flush pairs: gg = g>>1 -> resetw h-col (n0r>>3) + gg*8 + ni*2.
            const int row = t >> 2, gg = t & 3;
            const unsigned qv = *(const unsigned*)(qbuf + row * 8 + gg * 2);
            *(unsigned*)(resetw + (size_t)(m0 + row) * FD + D_IN + (n0r >> 3) +
                         gg * 8 + ni * 2) = qv;
        }
    }
}

// ---------------------------------------------------------------------------
// GEMM: [M,K](f16) @ [N,K](f16)^T, BMx128 tile, BK=64, m97-style.
// Kept for the detect path (BM=64, EPI=0): qk = tanhf(acc + b_d[col]).
// ---------------------------------------------------------------------------
template <int BM, int EPI>
__global__ __launch_bounds__(256) void gemm_k(
    const __half* __restrict__ A, const __half* __restrict__ Bt,
    const float* __restrict__ biasA, const float* __restrict__ biasB, int nsplit,
    float* __restrict__ C, int Ncols,
    const float* __restrict__ state, __half* __restrict__ resetw,
    __half* __restrict__ skibuf, int K)
{
    extern __shared__ __align__(16) char smem[];
    __half* sA = (__half*)smem;                // [BM][64] swizzled
    __half* sB = (__half*)(smem + BM * 128);   // [128][64] swizzled

    const int t    = threadIdx.x;
    const int m0   = blockIdx.y * BM;
    const int n0   = blockIdx.x << 7;
    const int lane = t & 63;
    const int w    = t >> 6;
    const int m16  = lane & 15;
    const int quad = lane >> 4;
    constexpr int MI = BM / 32;       // m-frags per wave
    constexpr int IA = BM / 32;       // A staging instrs per wave
    const int wm = (w & 1) * (BM / 2);
    const int wn = (w >> 1) << 6;

    f32x4 acc[MI][4];
#pragma unroll
    for (int i = 0; i < MI; i++)
#pragma unroll
        for (int j = 0; j < 4; j++)
#pragma unroll
            for (int r = 0; r < 4; r++) acc[i][j][r] = 0.f;

    const __half* gAp[IA];
    const __half* lAp[IA];
#pragma unroll
    for (int i = 0; i < IA; i++) {
        const int off = w * (BM * 32) + i * 1024 + lane * 16;  // byte off in tile
        const int row = off >> 7;
        const int g   = ((off & 127) >> 4) ^ (row & 7);        // swizzled global granule
        gAp[i] = A + (size_t)(m0 + row) * K + g * 8;
        lAp[i] = sA + ((w * (BM * 32) + i * 1024) >> 1);
    }
    const __half* gBp[4];
    const __half* lBp[4];
#pragma unroll
    for (int i = 0; i < 4; i++) {
        const int off = w * 4096 + i * 1024 + lane * 16;
        const int row = off >> 7;
        const int g   = ((off & 127) >> 4) ^ (row & 7);
        gBp[i] = Bt + (size_t)(n0 + row) * K + g * 8;
        lBp[i] = sB + ((w * 4096 + i * 1024) >> 1);
    }

    for (int kt = 0; kt < K; kt += 64) {
        __syncthreads();
#pragma unroll
        for (int i = 0; i < IA; i++)
            __builtin_amdgcn_global_load_lds((glb_cv*)(gAp[i] + kt), (lds_v*)lAp[i], 16, 0, 0);
#pragma unroll
        for (int i = 0; i < 4; i++)
            __builtin_amdgcn_global_load_lds((glb_cv*)(gBp[i] + kt), (lds_v*)lBp[i], 16, 0, 0);
        __syncthreads();

#pragma unroll
        for (int s = 0; s < 2; s++) {
            f16x8 af[MI], bf[4];
#pragma unroll
            for (int mi = 0; mi < MI; mi++) {
                const int row = wm + mi * 16 + m16;
                const int gi  = (s * 4 + quad) ^ (row & 7);
                af[mi] = *(const f16x8*)(sA + row * 64 + gi * 8);
            }
#pragma unroll
            for (int ni = 0; ni < 4; ni++) {
                const int row = wn + ni * 16 + m16;
                const int gi  = (s * 4 + quad) ^ (row & 7);
                bf[ni] = *(const f16x8*)(sB + row * 64 + gi * 8);
            }
#pragma unroll
            for (int mi = 0; mi < MI; mi++)
#pragma unroll
                for (int ni = 0; ni < 4; ni++)
                    acc[mi][ni] = __builtin_amdgcn_mfma_f32_16x16x32_f16(
                        af[mi], bf[ni], acc[mi][ni], 0, 0, 0);
        }
    }

    if constexpr (EPI == 0) {
        // -------- detect: tanh + plain store (BM == 64) --------
#pragma unroll
        for (int mi = 0; mi < MI; mi++) {
#pragma unroll
            for (int ni = 0; ni < 4; ni++) {
                const int col = n0 + wn + ni * 16 + m16;
                const float bv = biasA[col];
#pragma unroll
                for (int r = 0; r < 4; r++) {
                    const int row = m0 + wm + mi * 16 + quad * 4 + r;
                    C[(size_t)row * Ncols + col] = tanhf(acc[mi][ni][r] + bv);
                }
            }
        }
    }
}

// ---------------------------------------------------------------------------
// E2: h_hat_next = ((1-ski)*h_hat + ski*qk) * exp(-el/tau); h_next = sum_m
// ---------------------------------------------------------------------------
__global__ __launch_bounds__(256) void final_kernel(
    const __half* __restrict__ skibuf, const float* __restrict__ state,
    const float* __restrict__ qk, const float* __restrict__ elapsed,
    float* __restrict__ out0, float* __restrict__ out1)
{
    const int idx = blockIdx.x * 256 + threadIdx.x;
    const int b = idx >> 9;
    const int u = idx & 511;

    const float INV_TAU[8] = {1.0f, 0.316227766016838f, 0.1f, 0.0316227766016838f,
                              0.01f, 0.00316227766016838f, 0.001f, 0.000316227766016838f};

    const uint4 sr = *(const uint4*)(skibuf + (size_t)b * NRU + u * 8);
    const __half2* sh = (const __half2*)&sr;
    float sk[8];
#pragma unroll
    for (int i = 0; i < 4; i++) {
        float2 f2 = __half22float2(sh[i]);
        sk[2 * i]     = f2.x;
        sk[2 * i + 1] = f2.y;
    }

    const float4* hh = (const float4*)(state + ((size_t)b * NRU + u * 8));
    float4 h0 = hh[0], h1 = hh[1];
    float h[8] = {h0.x, h0.y, h0.z, h0.w, h1.x, h1.y, h1.z, h1.w};

    const float q  = qk[(size_t)b * U_N + u];
    const float el = elapsed[b];

    float hn[8];
    float acc = 0.f;
#pragma unroll
    for (int i = 0; i < 8; i++) {
        const float et = __expf(-el * INV_TAU[i]);
        hn[i] = ((1.0f - sk[i]) * h[i] + sk[i] * q) * et;
        acc += hn[i];
    }

    float4* o = (float4*)(out1 + ((size_t)b * NRU + u * 8));
    o[0] = make_float4(hn[0], hn[1], hn[2], hn[3]);
    o[1] = make_float4(hn[4], hn[5], hn[6], hn[7]);
    out0[(size_t)b * U_N + u] = acc;
}

// ---------------------------------------------------------------------------
extern "C" void kernel_launch(void* const* d_in, const int* in_sizes, int n_in,
                              void* d_out, int out_size, void* d_ws, size_t ws_size,
                              hipStream_t stream)
{
    (void)in_sizes; (void)n_in; (void)out_size; (void)ws_size;

    const float* inputs  = (const float*)d_in[0];
    const float* elapsed = (const float*)d_in[1];
    const float* state   = (const float*)d_in[2];
    const float* W_r     = (const float*)d_in[3];
    const float* b_r     = (const float*)d_in[4];
    const float* W_d     = (const float*)d_in[5];
    const float* b_d     = (const float*)d_in[6];
    const float* W_u     = (const float*)d_in[7];
    const float* b_u     = (const float*)d_in[8];
    float* out = (float*)d_out;

    char* ws = (char*)d_ws;
    __half* fused  = (__half*)(ws);                         //  4 MB [2048,1024]
    __half* reset  = (__half*)(ws + ((size_t)4  << 20));    //  4 MB [2048,1024]
    __half* WruT   = (__half*)(ws + ((size_t)8  << 20));    // 16 MB [8192,1024]
    __half* WdT    = (__half*)(ws + ((size_t)24 << 20));    //  1 MB [512,1024]
    __half* skibuf = (__half*)(ws + ((size_t)25 << 20));    // 16 MB [2048,4096]
    float*  qk     = (float*) (ws + ((size_t)41 << 20));    //  4 MB [2048,512]

    prep_kernel<<<B_SZ, 256, 0, stream>>>(inputs, state, fused, reset);
    convT3_kernel<<<dim3(272, FD / 32), 256, 0, stream>>>(W_r, W_u, W_d, WruT, WdT);

    // combined r+u GEMM with fused gate epilogue: [2048,1024] x [8192,1024]^T
    // 256^2 tile, 4-phase counted-vmcnt schedule, 16 waves/block (4/SIMD).
    gemm_big<<<dim3(NRU2 / 256, B_SZ / 256), 1024, 0, stream>>>(
        fused, WruT, b_r, b_u, state, reset, skibuf);

    // detect GEMM: [2048,1024] x [512,1024]^T -> qk fp32 (tanh)
    gemm_k<64, 0><<<dim3(U_N / 128, B_SZ / 64), 256, 24576, stream>>>(
        reset, WdT, b_d, nullptr, 1 << 30, qk, U_N, nullptr, nullptr, nullptr, FD);

    final_kernel<<<(B_SZ * U_N) / 256, 256, 0, stream>>>(skibuf, state, qk, elapsed, out,
                                                         out + (size_t)B_SZ * U_N);
}

// Round 6
// 198.506 us; speedup vs baseline: 1.1720x; 1.1720x over previous
//
#include <hip/hip_runtime.h>
#include <hip/hip_fp16.h>
#include <cmath>

#define B_SZ 2048
#define D_IN 512
#define U_N  512
#define FD   1024   // D_IN + U_N
#define NRU  4096   // U_N * M_B
#define NRU2 8192   // combined r+u output cols

typedef _Float16 f16x8 __attribute__((ext_vector_type(8)));
typedef float    f32x4 __attribute__((ext_vector_type(4)));

typedef const __attribute__((address_space(1))) void glb_cv;
typedef __attribute__((address_space(3))) void lds_v;

#define TAB_INIT {0.0f, 1.15129254649702f, 2.30258509299405f, \
                  3.45387763949107f, 4.60517018598809f, 5.75646273248511f, \
                  6.90775527898214f, 8.05904782547916f}

// ---------------------------------------------------------------------------
// Fused P1+P2 (round-6): one launch, no LDS, both parts streaming-coalesced.
//
// Blocks [0,4352): transpose-convert W_r / W_u / W_d WITHOUT LDS.
//   Thread (n, k0): reads W[k0+s][n] for s=0..7 (lanes vary n -> each of the
//   8 loads is a full 256B coalesced segment), writes f16x8 (16B/lane,
//   contiguous in WruT/WdT row n). Old version wrote 2B/lane scalar halves
//   (~8x under-vectorized writes) -- that was the convT3 cost.
// Blocks [4352,6400): prep. h = sum_m state; fused=[f16(in),f16(h)];
//   reset[:,0:512]=f16(in). Unchanged body.
// ---------------------------------------------------------------------------
__global__ __launch_bounds__(256) void prep_conv_kernel(
    const float* __restrict__ inputs, const float* __restrict__ state,
    const float* __restrict__ W_r, const float* __restrict__ W_u,
    const float* __restrict__ W_d,
    __half* __restrict__ fused, __half* __restrict__ reset,
    __half* __restrict__ WruT, __half* __restrict__ WdT)
{
    const int bx = blockIdx.x;
    const int t  = threadIdx.x;

    if (bx < 4352) {
        const float* W;
        __half* Wt;
        int N, n, k0;
        if (bx < 2048) {            // W_r -> WruT[0:4096]
            W = W_r; Wt = WruT; N = NRU;
            n  = (bx & 15) * 256 + t;
            k0 = (bx >> 4) * 8;
        } else if (bx < 4096) {     // W_u -> WruT[4096:8192]
            const int b2 = bx - 2048;
            W = W_u; Wt = WruT + (size_t)NRU * FD; N = NRU;
            n  = (b2 & 15) * 256 + t;
            k0 = (b2 >> 4) * 8;
        } else {                    // W_d -> WdT
            const int b2 = bx - 4096;
            W = W_d; Wt = WdT; N = U_N;
            n  = (b2 & 1) * 256 + t;
            k0 = (b2 >> 1) * 8;
        }
        float v[8];
#pragma unroll
        for (int s = 0; s < 8; s++)
            v[s] = W[(size_t)(k0 + s) * N + n];
        f16x8 h;
#pragma unroll
        for (int s = 0; s < 8; s++)
            h[s] = (_Float16)v[s];
        *(f16x8*)(Wt + (size_t)n * FD + k0) = h;
        return;
    }

    const int b = bx - 4352;

    const float2 iv = *(const float2*)(inputs + (size_t)b * D_IN + t * 2);
    __half2 hv;
    hv.x = __float2half(iv.x);
    hv.y = __float2half(iv.y);
    *(__half2*)(fused + (size_t)b * FD + t * 2) = hv;
    *(__half2*)(reset + (size_t)b * FD + t * 2) = hv;

    const float4* sp = (const float4*)(state + (size_t)b * NRU + t * 16);
    float4 x0 = sp[0], x1 = sp[1], x2 = sp[2], x3 = sp[3];
    float s0 = (x0.x + x0.y) + (x0.z + x0.w) + (x1.x + x1.y) + (x1.z + x1.w);
    float s1 = (x2.x + x2.y) + (x2.z + x2.w) + (x3.x + x3.y) + (x3.z + x3.w);
    __half2 h2;
    h2.x = __float2half(s0);
    h2.y = __float2half(s1);
    *(__half2*)(fused + (size_t)b * FD + D_IN + t * 2) = h2;
}

// ---------------------------------------------------------------------------
// Big GEMM: 256x256 tile, 4-phase / 2-K-tile schedule, ONE barrier per phase.
// (Round-6: reverted to the round-4 512-thread version -- best measured,
// 46.5 us, MfmaUtil ~28%, VGPR 128, no spills. The 1024-thread variant
// clamped VGPR to 64 and spilled the accumulator: WRITE_SIZE 20->60 MB.)
//
// Schedule (4 loads = one operand group per phase):
//   P1: read bufE B-all + A-h0, MFMA Q0; stage bufO.A(t1)
//   P2: read bufE A-h1,         MFMA Q1; stage bufE.B(t2); WAITV(4)
//   P3: read bufO B-all + A-h0, MFMA Q0; stage bufE.A(t2)
//   P4: read bufO A-h1,         MFMA Q1; stage bufO.B(t3); WAITV(4)
// FIFO induction: after each end-even-phase WAITV(4), exactly the newest
// 4-load group remains in flight; every READ target retired >=1 barrier
// earlier; every STAGE overwrites a slot last read before the preceding
// barrier. Tail stages clamp tile idx (&15): inert, in-bounds; drained
// before the epilogue reuses LDS.
// Frags ROW-INTERLEAVED: acc[mi][ni] covers rows mi*32+wm16, cols ni*64+wn16.
// ---------------------------------------------------------------------------
__global__ __launch_bounds__(512, 2) void gemm_big(
    const __half* __restrict__ A, const __half* __restrict__ Bt,
    const float* __restrict__ b_r, const float* __restrict__ b_u,
    const float* __restrict__ state, __half* __restrict__ resetw,
    __half* __restrict__ skibuf)
{
    __shared__ __align__(16) char smem[131072];
    __half* SAh = (__half*)smem;

    const int t    = threadIdx.x;
    const int m0   = blockIdx.y << 8;
    const int n0   = blockIdx.x << 8;
    const int lane = t & 63;
    const int w    = t >> 6;
    const int wm16 = ((w >> 2) & 1) << 4;
    const int wn16 = (w & 3) << 4;
    const int m16  = lane & 15;
    const int quad = lane >> 4;
    const int g0   = (quad ^ (m16 & 7)) << 3;        // ks=0 granule (f16 units)
    const int g1   = ((quad + 4) ^ (m16 & 7)) << 3;  // ks=1 granule
    const int t8   = t << 3;                          // per-thread LDS dst (f16)
    const int trow = t >> 3;                          // 0..63
    const int gcol = ((t & 7) ^ (trow & 7)) << 3;    // pre-swizzled global granule

    const __half* gA = A  + (size_t)(m0 + trow) * FD + gcol;
    const __half* gB = Bt + (size_t)(n0 + trow) * FD + gcol;

    f32x4 acc[8][4];
#pragma unroll
    for (int a1 = 0; a1 < 8; a1++)
#pragma unroll
        for (int a2 = 0; a2 < 4; a2++)
            acc[a1][a2] = (f32x4){0.f, 0.f, 0.f, 0.f};

#define BARRIER() __builtin_amdgcn_s_barrier()
#define PRIO1 __builtin_amdgcn_s_setprio(1)
#define PRIO0 __builtin_amdgcn_s_setprio(0)
#define WAITV(n) do { asm volatile("s_waitcnt vmcnt(" #n ")" ::: "memory"); \
                      __builtin_amdgcn_sched_barrier(0); } while (0)
#define WAITL() do { asm volatile("s_waitcnt lgkmcnt(0)" ::: "memory"); \
                     __builtin_amdgcn_sched_barrier(0); } while (0)

// one half-tile (128 rows) = 2 x global_load_lds width 16
#define STAGE_A(buf, h, tt) do { \
        const __half* _s = gA + (size_t)((h) * 128) * FD + (tt) * 64; \
        __half* _d = SAh + (buf) * 32768 + (h) * 8192 + t8; \
        __builtin_amdgcn_global_load_lds((glb_cv*)_s, (lds_v*)_d, 16, 0, 0); \
        __builtin_amdgcn_global_load_lds((glb_cv*)(_s + (size_t)64 * FD), \
                                         (lds_v*)(_d + 4096), 16, 0, 0); } while (0)
#define STAGE_B(buf, h, tt) do { \
        const __half* _s = gB + (size_t)((h) * 128) * FD + (tt) * 64; \
        __half* _d = SAh + (buf) * 32768 + 16384 + (h) * 8192 + t8; \
        __builtin_amdgcn_global_load_lds((glb_cv*)_s, (lds_v*)_d, 16, 0, 0); \
        __builtin_amdgcn_global_load_lds((glb_cv*)(_s + (size_t)64 * FD), \
                                         (lds_v*)(_d + 4096), 16, 0, 0); } while (0)

#define READ_A(c, mh) do { _Pragma("unroll") \
    for (int mi2 = 0; mi2 < 4; mi2++) { \
        const __half* _ap = SAh + (c) * 32768 + \
            ((((mh) * 4 + mi2) * 32 + wm16 + m16) << 6); \
        af[mi2][0] = *(const f16x8*)(_ap + g0); \
        af[mi2][1] = *(const f16x8*)(_ap + g1); } } while (0)
#define READ_B_ALL(c) do { _Pragma("unroll") \
    for (int ni2 = 0; ni2 < 4; ni2++) { \
        const __half* _bp = SAh + (c) * 32768 + 16384 + \
            ((ni2 * 64 + wn16 + m16) << 6); \
        bf[ni2][0] = *(const f16x8*)(_bp + g0); \
        bf[ni2][1] = *(const f16x8*)(_bp + g1); } } while (0)

// all ks0 MFMAs first, then all ks1: dependency distance 1 -> 16
#define MFMA_Q(MH) do { _Pragma("unroll") \
    for (int ks = 0; ks < 2; ks++) { _Pragma("unroll") \
        for (int mi2 = 0; mi2 < 4; mi2++) { _Pragma("unroll") \
            for (int ni2 = 0; ni2 < 4; ni2++) { \
                acc[(MH)*4+mi2][ni2] = __builtin_amdgcn_mfma_f32_16x16x32_f16( \
                    af[mi2][ks], bf[ni2][ks], acc[(MH)*4+mi2][ni2], 0, 0, 0); } } } } while (0)

    // ---- prologue (as-if P2/P3/P4 of iter -1): bufE.B(t0), bufE.A(t0),
    // bufO.B(t1); retire the bufE groups, keep bufO.B in flight. ----
    STAGE_B(0, 0, 0); STAGE_B(0, 1, 0);
    STAGE_A(0, 0, 0); STAGE_A(0, 1, 0);
    STAGE_B(1, 0, 1); STAGE_B(1, 1, 1);
    WAITV(4);
    BARRIER();

#pragma unroll 1
    for (int i = 0; i < 8; i++) {
        const int t1 = (2 * i + 1) & 15, t2 = (2 * i + 2) & 15, t3 = (2 * i + 3) & 15;
        f16x8 af[4][2], bf[4][2];
        // ---- P1: tile 2i (bufE) quadrant 0 ----
        READ_B_ALL(0); READ_A(0, 0);
        STAGE_A(1, 0, t1); STAGE_A(1, 1, t1);
        WAITL(); PRIO1; MFMA_Q(0); PRIO0; BARRIER();
        // ---- P2: tile 2i quadrant 1 (B live in regs) ----
        READ_A(0, 1);
        STAGE_B(0, 0, t2); STAGE_B(0, 1, t2);
        WAITL(); PRIO1; MFMA_Q(1); PRIO0; WAITV(4); BARRIER();
        // ---- P3: tile 2i+1 (bufO) quadrant 0 ----
        READ_B_ALL(1); READ_A(1, 0);
        STAGE_A(0, 0, t2); STAGE_A(0, 1, t2);
        WAITL(); PRIO1; MFMA_Q(0); PRIO0; BARRIER();
        // ---- P4: tile 2i+1 quadrant 1 ----
        READ_A(1, 1);
        STAGE_B(1, 0, t3); STAGE_B(1, 1, t3);
        WAITL(); PRIO1; MFMA_Q(1); PRIO0; WAITV(4); BARRIER();
    }

    WAITV(0);          // drain tail prefetches before LDS reuse
    __syncthreads();

#undef BARRIER
#undef PRIO1
#undef PRIO0
#undef WAITV
#undef WAITL
#undef STAGE_A
#undef STAGE_B
#undef READ_A
#undef READ_B_ALL
#undef MFMA_Q

    // -------- fused CTGRU gate epilogue, 4 chunks of 64 f16 cols --------
    float*  ebuf = (float*)smem;                     // [256][68] (pad: 16B-aligned rows)
    __half* qbuf = (__half*)(smem + 256 * 68 * 4);   // [256][8]
    const bool is_r = (n0 < NRU);
    const float* bp = is_r ? b_r : b_u;
    const int n0r = is_r ? n0 : n0 - NRU;
    const float TAB[8] = TAB_INIT;

    for (int ni = 0; ni < 4; ni++) {
        const float bv = bp[n0r + ni * 64 + wn16 + m16];
#pragma unroll
        for (int mi = 0; mi < 8; mi++)
#pragma unroll
            for (int r = 0; r < 4; r++)
                ebuf[(mi * 32 + wm16 + quad * 4 + r) * 68 + wn16 + m16] =
                    acc[mi][ni][r] + bv;
        __syncthreads();

#pragma unroll
        for (int p = 0; p < 4; p++) {
            const int item = p * 512 + t;        // 0..2047 = 256 rows x 8 groups
            const int row = item >> 3, g = item & 7;
            const int b = m0 + row;
            const float* rp = ebuf + row * 68 + g * 8;
            float v[8];
            *(float4*)&v[0] = *(const float4*)rp;
            *(float4*)&v[4] = *(const float4*)(rp + 4);

            float e[8], sum = 0.f;
#pragma unroll
            for (int i2 = 0; i2 < 8; i2++) {
                float d = v[i2] - TAB[i2];
                e[i2] = __expf(-d * d);
                sum += e[i2];
            }
            const int colr = n0r + ni * 64 + g * 8;   // flat (u*8) col
            if (is_r) {
                const float4 h0 = *(const float4*)(state + (size_t)b * NRU + colr);
                const float4 h1 = *(const float4*)(state + (size_t)b * NRU + colr + 4);
                const float hv[8] = {h0.x, h0.y, h0.z, h0.w, h1.x, h1.y, h1.z, h1.w};
                float qn = 0.f;
#pragma unroll
                for (int i2 = 0; i2 < 8; i2++) qn += e[i2] * hv[i2];
                qbuf[row * 8 + g] = __float2half(qn / sum);
            } else {
                const float inv = 1.0f / sum;
                __half2 o[4];
#pragma unroll
                for (int i2 = 0; i2 < 4; i2++) {
                    o[i2].x = __float2half(e[2 * i2] * inv);
                    o[i2].y = __float2half(e[2 * i2 + 1] * inv);
                }
                *(uint4*)(skibuf + (size_t)b * NRU + colr) = *(uint4*)o;
            }
        }
        __syncthreads();
        if (is_r) {
            const int row = t >> 1, lg = (t & 1) << 2;
            uint2 qv = *(uint2*)(qbuf + row * 8 + lg);
            *(uint2*)(resetw + (size_t)(m0 + row) * FD + D_IN + (n0r >> 3) + ni * 8 + lg) = qv;
        }
    }
}

// ---------------------------------------------------------------------------
// GEMM: [M,K](f16) @ [N,K](f16)^T, BMx128 tile, BK=64, m97-style.
// Detect path (BM=32, EPI=0): qk = tanhf(acc + b_d[col]).
// Round-6: BM 64 -> 32 so grid = (4,64) = 256 blocks = 1 block/CU (the old
// 128-block grid left half the GPU idle).
// ---------------------------------------------------------------------------
template <int BM, int EPI>
__global__ __launch_bounds__(256) void gemm_k(
    const __half* __restrict__ A, const __half* __restrict__ Bt,
    const float* __restrict__ biasA, const float* __restrict__ biasB, int nsplit,
    float* __restrict__ C, int Ncols,
    const float* __restrict__ state, __half* __restrict__ resetw,
    __half* __restrict__ skibuf, int K)
{
    extern __shared__ __align__(16) char smem[];
    __half* sA = (__half*)smem;                // [BM][64] swizzled
    __half* sB = (__half*)(smem + BM * 128);   // [128][64] swizzled

    const int t    = threadIdx.x;
    const int m0   = blockIdx.y * BM;
    const int n0   = blockIdx.x << 7;
    const int lane = t & 63;
    const int w    = t >> 6;
    const int m16  = lane & 15;
    const int quad = lane >> 4;
    constexpr int MI = BM / 32;       // m-frags per wave
    constexpr int IA = BM / 32;       // A staging instrs per wave
    const int wm = (w & 1) * (BM / 2);
    const int wn = (w >> 1) << 6;

    f32x4 acc[MI][4];
#pragma unroll
    for (int i = 0; i < MI; i++)
#pragma unroll
        for (int j = 0; j < 4; j++)
#pragma unroll
            for (int r = 0; r < 4; r++) acc[i][j][r] = 0.f;

    const __half* gAp[IA];
    const __half* lAp[IA];
#pragma unroll
    for (int i = 0; i < IA; i++) {
        const int off = w * (BM * 32) + i * 1024 + lane * 16;  // byte off in tile
        const int row = off >> 7;
        const int g   = ((off & 127) >> 4) ^ (row & 7);        // swizzled global granule
        gAp[i] = A + (size_t)(m0 + row) * K + g * 8;
        lAp[i] = sA + ((w * (BM * 32) + i * 1024) >> 1);
    }
    const __half* gBp[4];
    const __half* lBp[4];
#pragma unroll
    for (int i = 0; i < 4; i++) {
        const int off = w * 4096 + i * 1024 + lane * 16;
        const int row = off >> 7;
        const int g   = ((off & 127) >> 4) ^ (row & 7);
        gBp[i] = Bt + (size_t)(n0 + row) * K + g * 8;
        lBp[i] = sB + ((w * 4096 + i * 1024) >> 1);
    }

    for (int kt = 0; kt < K; kt += 64) {
        __syncthreads();
#pragma unroll
        for (int i = 0; i < IA; i++)
            __builtin_amdgcn_global_load_lds((glb_cv*)(gAp[i] + kt), (lds_v*)lAp[i], 16, 0, 0);
#pragma unroll
        for (int i = 0; i < 4; i++)
            __builtin_amdgcn_global_load_lds((glb_cv*)(gBp[i] + kt), (lds_v*)lBp[i], 16, 0, 0);
        __syncthreads();

#pragma unroll
        for (int s = 0; s < 2; s++) {
            f16x8 af[MI], bf[4];
#pragma unroll
            for (int mi = 0; mi < MI; mi++) {
                const int row = wm + mi * 16 + m16;
                const int gi  = (s * 4 + quad) ^ (row & 7);
                af[mi] = *(const f16x8*)(sA + row * 64 + gi * 8);
            }
#pragma unroll
            for (int ni = 0; ni < 4; ni++) {
                const int row = wn + ni * 16 + m16;
                const int gi  = (s * 4 + quad) ^ (row & 7);
                bf[ni] = *(const f16x8*)(sB + row * 64 + gi * 8);
            }
#pragma unroll
            for (int mi = 0; mi < MI; mi++)
#pragma unroll
                for (int ni = 0; ni < 4; ni++)
                    acc[mi][ni] = __builtin_amdgcn_mfma_f32_16x16x32_f16(
                        af[mi], bf[ni], acc[mi][ni], 0, 0, 0);
        }
    }

    if constexpr (EPI == 0) {
        // -------- detect: tanh + plain store --------
#pragma unroll
        for (int mi = 0; mi < MI; mi++) {
#pragma unroll
            for (int ni = 0; ni < 4; ni++) {
                const int col = n0 + wn + ni * 16 + m16;
                const float bv = biasA[col];
#pragma unroll
                for (int r = 0; r < 4; r++) {
                    const int row = m0 + wm + mi * 16 + quad * 4 + r;
                    C[(size_t)row * Ncols + col] = tanhf(acc[mi][ni][r] + bv);
                }
            }
        }
    }
}

// ---------------------------------------------------------------------------
// E2: h_hat_next = ((1-ski)*h_hat + ski*qk) * exp(-el/tau); h_next = sum_m
// ---------------------------------------------------------------------------
__global__ __launch_bounds__(256) void final_kernel(
    const __half* __restrict__ skibuf, const float* __restrict__ state,
    const float* __restrict__ qk, const float* __restrict__ elapsed,
    float* __restrict__ out0, float* __restrict__ out1)
{
    const int idx = blockIdx.x * 256 + threadIdx.x;
    const int b = idx >> 9;
    const int u = idx & 511;

    const float INV_TAU[8] = {1.0f, 0.316227766016838f, 0.1f, 0.0316227766016838f,
                              0.01f, 0.00316227766016838f, 0.001f, 0.000316227766016838f};

    const uint4 sr = *(const uint4*)(skibuf + (size_t)b * NRU + u * 8);
    const __half2* sh = (const __half2*)&sr;
    float sk[8];
#pragma unroll
    for (int i = 0; i < 4; i++) {
        float2 f2 = __half22float2(sh[i]);
        sk[2 * i]     = f2.x;
        sk[2 * i + 1] = f2.y;
    }

    const float4* hh = (const float4*)(state + ((size_t)b * NRU + u * 8));
    float4 h0 = hh[0], h1 = hh[1];
    float h[8] = {h0.x, h0.y, h0.z, h0.w, h1.x, h1.y, h1.z, h1.w};

    const float q  = qk[(size_t)b * U_N + u];
    const float el = elapsed[b];

    float hn[8];
    float acc = 0.f;
#pragma unroll
    for (int i = 0; i < 8; i++) {
        const float et = __expf(-el * INV_TAU[i]);
        hn[i] = ((1.0f - sk[i]) * h[i] + sk[i] * q) * et;
        acc += hn[i];
    }

    float4* o = (float4*)(out1 + ((size_t)b * NRU + u * 8));
    o[0] = make_float4(hn[0], hn[1], hn[2], hn[3]);
    o[1] = make_float4(hn[4], hn[5], hn[6], hn[7]);
    out0[(size_t)b * U_N + u] = acc;
}

// ---------------------------------------------------------------------------
extern "C" void kernel_launch(void* const* d_in, const int* in_sizes, int n_in,
                              void* d_out, int out_size, void* d_ws, size_t ws_size,
                              hipStream_t stream)
{
    (void)in_sizes; (void)n_in; (void)out_size; (void)ws_size;

    const float* inputs  = (const float*)d_in[0];
    const float* elapsed = (const float*)d_in[1];
    const float* state   = (const float*)d_in[2];
    const float* W_r     = (const float*)d_in[3];
    const float* b_r     = (const float*)d_in[4];
    const float* W_d     = (const float*)d_in[5];
    const float* b_d     = (const float*)d_in[6];
    const float* W_u     = (const float*)d_in[7];
    const float* b_u     = (const float*)d_in[8];
    float* out = (float*)d_out;

    char* ws = (char*)d_ws;
    __half* fused  = (__half*)(ws);                         //  4 MB [2048,1024]
    __half* reset  = (__half*)(ws + ((size_t)4  << 20));    //  4 MB [2048,1024]
    __half* WruT   = (__half*)(ws + ((size_t)8  << 20));    // 16 MB [8192,1024]
    __half* WdT    = (__half*)(ws + ((size_t)24 << 20));    //  1 MB [512,1024]
    __half* skibuf = (__half*)(ws + ((size_t)25 << 20));    // 16 MB [2048,4096]
    float*  qk     = (float*) (ws + ((size_t)41 << 20));    //  4 MB [2048,512]

    // fused prep + weight transpose-convert (one launch, coalesced both ways)
    prep_conv_kernel<<<6400, 256, 0, stream>>>(inputs, state, W_r, W_u, W_d,
                                               fused, reset, WruT, WdT);

    // combined r+u GEMM with fused gate epilogue: [2048,1024] x [8192,1024]^T
    // 256^2 tile, 4-phase counted-vmcnt schedule, 512 thr (round-4 version).
    gemm_big<<<dim3(NRU2 / 256, B_SZ / 256), 512, 0, stream>>>(
        fused, WruT, b_r, b_u, state, reset, skibuf);

    // detect GEMM: [2048,1024] x [512,1024]^T -> qk fp32 (tanh); BM=32 ->
    // grid (4,64) = 256 blocks = full machine.
    gemm_k<32, 0><<<dim3(U_N / 128, B_SZ / 32), 256, 20480, stream>>>(
        reset, WdT, b_d, nullptr, 1 << 30, qk, U_N, nullptr, nullptr, nullptr, FD);

    final_kernel<<<(B_SZ * U_N) / 256, 256, 0, stream>>>(skibuf, state, qk, elapsed, out,
                                                         out + (size_t)B_SZ * U_N);
}

// Round 7
// 187.992 us; speedup vs baseline: 1.2375x; 1.0559x over previous
//
#include <hip/hip_runtime.h>
#include <hip/hip_fp16.h>
#include <cmath>

#define B_SZ 2048
#define D_IN 512
#define U_N  512
#define FD   1024   // D_IN + U_N
#define NRU  4096   // U_N * M_B
#define NRU2 8192   // combined r+u output cols

typedef _Float16 f16x8 __attribute__((ext_vector_type(8)));
typedef float    f32x4 __attribute__((ext_vector_type(4)));

typedef const __attribute__((address_space(1))) void glb_cv;
typedef __attribute__((address_space(3))) void lds_v;

#define TAB_INIT {0.0f, 1.15129254649702f, 2.30258509299405f, \
                  3.45387763949107f, 4.60517018598809f, 5.75646273248511f, \
                  6.90775527898214f, 8.05904782547916f}

#define INV_TAU_INIT {1.0f, 0.316227766016838f, 0.1f, 0.0316227766016838f, \
                      0.01f, 0.00316227766016838f, 0.001f, 0.000316227766016838f}

// ---------------------------------------------------------------------------
// Fused P1+P2 (round-7): weight transpose via LDS tiles with COALESCED writes.
// Round-6 version wrote 16B per lane at 2KB stride (every write its own cache
// line, ~4x write amplification on 17MB). Now: 32n x 256k f32 tile ->
// LDS f16 [32][264] -> phase-2 writes 512B contiguous per 32-lane group.
// Reads stay coalesced (128B segments per 32-lane group).
// Blocks [0,1088): W_r (512) / W_u (512) / W_d (64).
// Blocks [1088,3136): prep (unchanged body).
// ---------------------------------------------------------------------------
__global__ __launch_bounds__(256) void prep_conv_kernel(
    const float* __restrict__ inputs, const float* __restrict__ state,
    const float* __restrict__ W_r, const float* __restrict__ W_u,
    const float* __restrict__ W_d,
    __half* __restrict__ fused, __half* __restrict__ reset,
    __half* __restrict__ WruT, __half* __restrict__ WdT)
{
    const int bx = blockIdx.x;
    const int t  = threadIdx.x;

    if (bx < 1088) {
        __shared__ __half lt[32][264];   // 264: 16B-aligned rows (528B)
        const float* W;
        __half* Wt;
        int N, b2;
        if (bx < 512)       { W = W_r; Wt = WruT;                    N = NRU; b2 = bx; }
        else if (bx < 1024) { W = W_u; Wt = WruT + (size_t)NRU * FD; N = NRU; b2 = bx - 512; }
        else                { W = W_d; Wt = WdT;                     N = U_N; b2 = bx - 1024; }
        const int n0 = (b2 >> 2) * 32;
        const int kt = (b2 & 3) * 256;

        // phase 1: coalesced read (lanes vary n), convert, LDS[n][k]
        const int n_off = t & 31, kg = t >> 5;   // kg 0..7
#pragma unroll
        for (int s = 0; s < 32; s++) {
            const int kr = kg + s * 8;           // covers 0..255
            lt[n_off][kr] = __float2half(W[(size_t)(kt + kr) * N + n0 + n_off]);
        }
        __syncthreads();

        // phase 2: contiguous write -- 32 lanes of a group share one n-row,
        // write consecutive 16B chunks = 512B segments.
        const int c = t & 31, ng = t >> 5;       // ng 0..7
#pragma unroll
        for (int p = 0; p < 4; p++) {
            const int n = ng + p * 8;            // 0..31
            f16x8 v = *(const f16x8*)&lt[n][c * 8];
            *(f16x8*)(Wt + (size_t)(n0 + n) * FD + kt + c * 8) = v;
        }
        return;
    }

    const int b = bx - 1088;

    const float2 iv = *(const float2*)(inputs + (size_t)b * D_IN + t * 2);
    __half2 hv;
    hv.x = __float2half(iv.x);
    hv.y = __float2half(iv.y);
    *(__half2*)(fused + (size_t)b * FD + t * 2) = hv;
    *(__half2*)(reset + (size_t)b * FD + t * 2) = hv;

    const float4* sp = (const float4*)(state + (size_t)b * NRU + t * 16);
    float4 x0 = sp[0], x1 = sp[1], x2 = sp[2], x3 = sp[3];
    float s0 = (x0.x + x0.y) + (x0.z + x0.w) + (x1.x + x1.y) + (x1.z + x1.w);
    float s1 = (x2.x + x2.y) + (x2.z + x2.w) + (x3.x + x3.y) + (x3.z + x3.w);
    __half2 h2;
    h2.x = __float2half(s0);
    h2.y = __float2half(s1);
    *(__half2*)(fused + (size_t)b * FD + D_IN + t * 2) = h2;
}

// ---------------------------------------------------------------------------
// Big GEMM: 256x256 tile, 4-phase / 2-K-tile schedule, ONE barrier per phase.
// (Unchanged from round 4/6 -- best measured: 46 us, MfmaUtil ~28%, VGPR 128.)
//
// Schedule (4 loads = one operand group per phase):
//   P1: read bufE B-all + A-h0, MFMA Q0; stage bufO.A(t1)
//   P2: read bufE A-h1,         MFMA Q1; stage bufE.B(t2); WAITV(4)
//   P3: read bufO B-all + A-h0, MFMA Q0; stage bufE.A(t2)
//   P4: read bufO A-h1,         MFMA Q1; stage bufO.B(t3); WAITV(4)
// FIFO induction: after each end-even-phase WAITV(4), exactly the newest
// 4-load group remains in flight; every READ target retired >=1 barrier
// earlier; every STAGE overwrites a slot last read before the preceding
// barrier. Tail stages clamp tile idx (&15): inert, in-bounds; drained
// before the epilogue reuses LDS.
// Frags ROW-INTERLEAVED: acc[mi][ni] covers rows mi*32+wm16, cols ni*64+wn16.
// ---------------------------------------------------------------------------
__global__ __launch_bounds__(512, 2) void gemm_big(
    const __half* __restrict__ A, const __half* __restrict__ Bt,
    const float* __restrict__ b_r, const float* __restrict__ b_u,
    const float* __restrict__ state, __half* __restrict__ resetw,
    __half* __restrict__ skibuf)
{
    __shared__ __align__(16) char smem[131072];
    __half* SAh = (__half*)smem;

    const int t    = threadIdx.x;
    const int m0   = blockIdx.y << 8;
    const int n0   = blockIdx.x << 8;
    const int lane = t & 63;
    const int w    = t >> 6;
    const int wm16 = ((w >> 2) & 1) << 4;
    const int wn16 = (w & 3) << 4;
    const int m16  = lane & 15;
    const int quad = lane >> 4;
    const int g0   = (quad ^ (m16 & 7)) << 3;        // ks=0 granule (f16 units)
    const int g1   = ((quad + 4) ^ (m16 & 7)) << 3;  // ks=1 granule
    const int t8   = t << 3;                          // per-thread LDS dst (f16)
    const int trow = t >> 3;                          // 0..63
    const int gcol = ((t & 7) ^ (trow & 7)) << 3;    // pre-swizzled global granule

    const __half* gA = A  + (size_t)(m0 + trow) * FD + gcol;
    const __half* gB = Bt + (size_t)(n0 + trow) * FD + gcol;

    f32x4 acc[8][4];
#pragma unroll
    for (int a1 = 0; a1 < 8; a1++)
#pragma unroll
        for (int a2 = 0; a2 < 4; a2++)
            acc[a1][a2] = (f32x4){0.f, 0.f, 0.f, 0.f};

#define BARRIER() __builtin_amdgcn_s_barrier()
#define PRIO1 __builtin_amdgcn_s_setprio(1)
#define PRIO0 __builtin_amdgcn_s_setprio(0)
#define WAITV(n) do { asm volatile("s_waitcnt vmcnt(" #n ")" ::: "memory"); \
                      __builtin_amdgcn_sched_barrier(0); } while (0)
#define WAITL() do { asm volatile("s_waitcnt lgkmcnt(0)" ::: "memory"); \
                     __builtin_amdgcn_sched_barrier(0); } while (0)

// one half-tile (128 rows) = 2 x global_load_lds width 16
#define STAGE_A(buf, h, tt) do { \
        const __half* _s = gA + (size_t)((h) * 128) * FD + (tt) * 64; \
        __half* _d = SAh + (buf) * 32768 + (h) * 8192 + t8; \
        __builtin_amdgcn_global_load_lds((glb_cv*)_s, (lds_v*)_d, 16, 0, 0); \
        __builtin_amdgcn_global_load_lds((glb_cv*)(_s + (size_t)64 * FD), \
                                         (lds_v*)(_d + 4096), 16, 0, 0); } while (0)
#define STAGE_B(buf, h, tt) do { \
        const __half* _s = gB + (size_t)((h) * 128) * FD + (tt) * 64; \
        __half* _d = SAh + (buf) * 32768 + 16384 + (h) * 8192 + t8; \
        __builtin_amdgcn_global_load_lds((glb_cv*)_s, (lds_v*)_d, 16, 0, 0); \
        __builtin_amdgcn_global_load_lds((glb_cv*)(_s + (size_t)64 * FD), \
                                         (lds_v*)(_d + 4096), 16, 0, 0); } while (0)

#define READ_A(c, mh) do { _Pragma("unroll") \
    for (int mi2 = 0; mi2 < 4; mi2++) { \
        const __half* _ap = SAh + (c) * 32768 + \
            ((((mh) * 4 + mi2) * 32 + wm16 + m16) << 6); \
        af[mi2][0] = *(const f16x8*)(_ap + g0); \
        af[mi2][1] = *(const f16x8*)(_ap + g1); } } while (0)
#define READ_B_ALL(c) do { _Pragma("unroll") \
    for (int ni2 = 0; ni2 < 4; ni2++) { \
        const __half* _bp = SAh + (c) * 32768 + 16384 + \
            ((ni2 * 64 + wn16 + m16) << 6); \
        bf[ni2][0] = *(const f16x8*)(_bp + g0); \
        bf[ni2][1] = *(const f16x8*)(_bp + g1); } } while (0)

// all ks0 MFMAs first, then all ks1: dependency distance 1 -> 16
#define MFMA_Q(MH) do { _Pragma("unroll") \
    for (int ks = 0; ks < 2; ks++) { _Pragma("unroll") \
        for (int mi2 = 0; mi2 < 4; mi2++) { _Pragma("unroll") \
            for (int ni2 = 0; ni2 < 4; ni2++) { \
                acc[(MH)*4+mi2][ni2] = __builtin_amdgcn_mfma_f32_16x16x32_f16( \
                    af[mi2][ks], bf[ni2][ks], acc[(MH)*4+mi2][ni2], 0, 0, 0); } } } } while (0)

    // ---- prologue (as-if P2/P3/P4 of iter -1): bufE.B(t0), bufE.A(t0),
    // bufO.B(t1); retire the bufE groups, keep bufO.B in flight. ----
    STAGE_B(0, 0, 0); STAGE_B(0, 1, 0);
    STAGE_A(0, 0, 0); STAGE_A(0, 1, 0);
    STAGE_B(1, 0, 1); STAGE_B(1, 1, 1);
    WAITV(4);
    BARRIER();

#pragma unroll 1
    for (int i = 0; i < 8; i++) {
        const int t1 = (2 * i + 1) & 15, t2 = (2 * i + 2) & 15, t3 = (2 * i + 3) & 15;
        f16x8 af[4][2], bf[4][2];
        // ---- P1: tile 2i (bufE) quadrant 0 ----
        READ_B_ALL(0); READ_A(0, 0);
        STAGE_A(1, 0, t1); STAGE_A(1, 1, t1);
        WAITL(); PRIO1; MFMA_Q(0); PRIO0; BARRIER();
        // ---- P2: tile 2i quadrant 1 (B live in regs) ----
        READ_A(0, 1);
        STAGE_B(0, 0, t2); STAGE_B(0, 1, t2);
        WAITL(); PRIO1; MFMA_Q(1); PRIO0; WAITV(4); BARRIER();
        // ---- P3: tile 2i+1 (bufO) quadrant 0 ----
        READ_B_ALL(1); READ_A(1, 0);
        STAGE_A(0, 0, t2); STAGE_A(0, 1, t2);
        WAITL(); PRIO1; MFMA_Q(0); PRIO0; BARRIER();
        // ---- P4: tile 2i+1 quadrant 1 ----
        READ_A(1, 1);
        STAGE_B(1, 0, t3); STAGE_B(1, 1, t3);
        WAITL(); PRIO1; MFMA_Q(1); PRIO0; WAITV(4); BARRIER();
    }

    WAITV(0);          // drain tail prefetches before LDS reuse
    __syncthreads();

#undef BARRIER
#undef PRIO1
#undef PRIO0
#undef WAITV
#undef WAITL
#undef STAGE_A
#undef STAGE_B
#undef READ_A
#undef READ_B_ALL
#undef MFMA_Q

    // -------- fused CTGRU gate epilogue, 4 chunks of 64 f16 cols --------
    float*  ebuf = (float*)smem;                     // [256][68] (pad: 16B-aligned rows)
    __half* qbuf = (__half*)(smem + 256 * 68 * 4);   // [256][8]
    const bool is_r = (n0 < NRU);
    const float* bp = is_r ? b_r : b_u;
    const int n0r = is_r ? n0 : n0 - NRU;
    const float TAB[8] = TAB_INIT;

    for (int ni = 0; ni < 4; ni++) {
        const float bv = bp[n0r + ni * 64 + wn16 + m16];
#pragma unroll
        for (int mi = 0; mi < 8; mi++)
#pragma unroll
            for (int r = 0; r < 4; r++)
                ebuf[(mi * 32 + wm16 + quad * 4 + r) * 68 + wn16 + m16] =
                    acc[mi][ni][r] + bv;
        __syncthreads();

#pragma unroll
        for (int p = 0; p < 4; p++) {
            const int item = p * 512 + t;        // 0..2047 = 256 rows x 8 groups
            const int row = item >> 3, g = item & 7;
            const int b = m0 + row;
            const float* rp = ebuf + row * 68 + g * 8;
            float v[8];
            *(float4*)&v[0] = *(const float4*)rp;
            *(float4*)&v[4] = *(const float4*)(rp + 4);

            float e[8], sum = 0.f;
#pragma unroll
            for (int i2 = 0; i2 < 8; i2++) {
                float d = v[i2] - TAB[i2];
                e[i2] = __expf(-d * d);
                sum += e[i2];
            }
            const int colr = n0r + ni * 64 + g * 8;   // flat (u*8) col
            if (is_r) {
                const float4 h0 = *(const float4*)(state + (size_t)b * NRU + colr);
                const float4 h1 = *(const float4*)(state + (size_t)b * NRU + colr + 4);
                const float hv[8] = {h0.x, h0.y, h0.z, h0.w, h1.x, h1.y, h1.z, h1.w};
                float qn = 0.f;
#pragma unroll
                for (int i2 = 0; i2 < 8; i2++) qn += e[i2] * hv[i2];
                qbuf[row * 8 + g] = __float2half(qn / sum);
            } else {
                const float inv = 1.0f / sum;
                __half2 o[4];
#pragma unroll
                for (int i2 = 0; i2 < 4; i2++) {
                    o[i2].x = __float2half(e[2 * i2] * inv);
                    o[i2].y = __float2half(e[2 * i2 + 1] * inv);
                }
                *(uint4*)(skibuf + (size_t)b * NRU + colr) = *(uint4*)o;
            }
        }
        __syncthreads();
        if (is_r) {
            const int row = t >> 1, lg = (t & 1) << 2;
            uint2 qv = *(uint2*)(qbuf + row * 8 + lg);
            *(uint2*)(resetw + (size_t)(m0 + row) * FD + D_IN + (n0r >> 3) + ni * 8 + lg) = qv;
        }
    }
}

// ---------------------------------------------------------------------------
// Detect GEMM + FUSED FINAL (round-7): [2048,1024] x [512,1024]^T, BM=32,
// grid (4,64) = 256 blocks = 1/CU. Epilogue computes qk = tanh(acc + b_d)
// in-register and applies the CTGRU update directly -- final_kernel and the
// qk round-trip (8 MB) are gone. Per output element (b,u):
//   h_hat_next[b,u,i] = ((1-ski)*h_hat + ski*qk) * exp(-el/tau_i)
//   out0[b,u] = sum_i h_hat_next.  All element-local (no cross-thread comm).
// exp(-el/tau) cached per row (reused across 4 ni -> 4x fewer expf).
// ---------------------------------------------------------------------------
__global__ __launch_bounds__(256) void gemm_detect(
    const __half* __restrict__ A, const __half* __restrict__ Bt,
    const float* __restrict__ b_d,
    const __half* __restrict__ skibuf, const float* __restrict__ state,
    const float* __restrict__ elapsed,
    float* __restrict__ out0, float* __restrict__ out1)
{
    constexpr int BM = 32;
    constexpr int K  = FD;
    __shared__ __align__(16) char smem[20480];
    __half* sA = (__half*)smem;                // [32][64] swizzled
    __half* sB = (__half*)(smem + BM * 128);   // [128][64] swizzled

    const int t    = threadIdx.x;
    const int m0   = blockIdx.y * BM;
    const int n0   = blockIdx.x << 7;
    const int lane = t & 63;
    const int w    = t >> 6;
    const int m16  = lane & 15;
    const int quad = lane >> 4;
    const int wm = (w & 1) * (BM / 2);
    const int wn = (w >> 1) << 6;

    f32x4 acc[4];
#pragma unroll
    for (int j = 0; j < 4; j++)
#pragma unroll
        for (int r = 0; r < 4; r++) acc[j][r] = 0.f;

    const __half* gAp;
    const __half* lAp;
    {
        const int off = w * (BM * 32) + lane * 16;             // byte off in tile
        const int row = off >> 7;
        const int g   = ((off & 127) >> 4) ^ (row & 7);
        gAp = A + (size_t)(m0 + row) * K + g * 8;
        lAp = sA + ((w * (BM * 32)) >> 1);
    }
    const __half* gBp[4];
    const __half* lBp[4];
#pragma unroll
    for (int i = 0; i < 4; i++) {
        const int off = w * 4096 + i * 1024 + lane * 16;
        const int row = off >> 7;
        const int g   = ((off & 127) >> 4) ^ (row & 7);
        gBp[i] = Bt + (size_t)(n0 + row) * K + g * 8;
        lBp[i] = sB + ((w * 4096 + i * 1024) >> 1);
    }

    for (int kt = 0; kt < K; kt += 64) {
        __syncthreads();
        __builtin_amdgcn_global_load_lds((glb_cv*)(gAp + kt), (lds_v*)lAp, 16, 0, 0);
#pragma unroll
        for (int i = 0; i < 4; i++)
            __builtin_amdgcn_global_load_lds((glb_cv*)(gBp[i] + kt), (lds_v*)lBp[i], 16, 0, 0);
        __syncthreads();

#pragma unroll
        for (int s = 0; s < 2; s++) {
            f16x8 af, bf[4];
            {
                const int row = wm + m16;
                const int gi  = (s * 4 + quad) ^ (row & 7);
                af = *(const f16x8*)(sA + row * 64 + gi * 8);
            }
#pragma unroll
            for (int ni = 0; ni < 4; ni++) {
                const int row = wn + ni * 16 + m16;
                const int gi  = (s * 4 + quad) ^ (row & 7);
                bf[ni] = *(const f16x8*)(sB + row * 64 + gi * 8);
            }
#pragma unroll
            for (int ni = 0; ni < 4; ni++)
                acc[ni] = __builtin_amdgcn_mfma_f32_16x16x32_f16(af, bf[ni], acc[ni], 0, 0, 0);
        }
    }

    // -------- fused epilogue: tanh + CTGRU final update --------
    const float INV_TAU[8] = INV_TAU_INIT;
    float bv[4];
#pragma unroll
    for (int ni = 0; ni < 4; ni++) bv[ni] = b_d[n0 + wn + ni * 16 + m16];

#pragma unroll
    for (int r = 0; r < 4; r++) {
        const int row = m0 + wm + quad * 4 + r;
        const float el = elapsed[row];
        float et[8];
#pragma unroll
        for (int i = 0; i < 8; i++) et[i] = __expf(-el * INV_TAU[i]);

#pragma unroll
        for (int ni = 0; ni < 4; ni++) {
            const int col = n0 + wn + ni * 16 + m16;       // u index
            const float q = tanhf(acc[ni][r] + bv[ni]);

            const uint4 sr = *(const uint4*)(skibuf + (size_t)row * NRU + col * 8);
            const __half2* sh = (const __half2*)&sr;
            float sk[8];
#pragma unroll
            for (int i = 0; i < 4; i++) {
                float2 f2 = __half22float2(sh[i]);
                sk[2 * i]     = f2.x;
                sk[2 * i + 1] = f2.y;
            }
            const float4* hh = (const float4*)(state + ((size_t)row * NRU + col * 8));
            float4 h0 = hh[0], h1 = hh[1];
            float h[8] = {h0.x, h0.y, h0.z, h0.w, h1.x, h1.y, h1.z, h1.w};

            float hn[8];
            float accs = 0.f;
#pragma unroll
            for (int i = 0; i < 8; i++) {
                hn[i] = ((1.0f - sk[i]) * h[i] + sk[i] * q) * et[i];
                accs += hn[i];
            }
            float4* o = (float4*)(out1 + ((size_t)row * NRU + col * 8));
            o[0] = make_float4(hn[0], hn[1], hn[2], hn[3]);
            o[1] = make_float4(hn[4], hn[5], hn[6], hn[7]);
            out0[(size_t)row * U_N + col] = accs;
        }
    }
}

// ---------------------------------------------------------------------------
extern "C" void kernel_launch(void* const* d_in, const int* in_sizes, int n_in,
                              void* d_out, int out_size, void* d_ws, size_t ws_size,
                              hipStream_t stream)
{
    (void)in_sizes; (void)n_in; (void)out_size; (void)ws_size;

    const float* inputs  = (const float*)d_in[0];
    const float* elapsed = (const float*)d_in[1];
    const float* state   = (const float*)d_in[2];
    const float* W_r     = (const float*)d_in[3];
    const float* b_r     = (const float*)d_in[4];
    const float* W_d     = (const float*)d_in[5];
    const float* b_d     = (const float*)d_in[6];
    const float* W_u     = (const float*)d_in[7];
    const float* b_u     = (const float*)d_in[8];
    float* out = (float*)d_out;

    char* ws = (char*)d_ws;
    __half* fused  = (__half*)(ws);                         //  4 MB [2048,1024]
    __half* reset  = (__half*)(ws + ((size_t)4  << 20));    //  4 MB [2048,1024]
    __half* WruT   = (__half*)(ws + ((size_t)8  << 20));    // 16 MB [8192,1024]
    __half* WdT    = (__half*)(ws + ((size_t)24 << 20));    //  1 MB [512,1024]
    __half* skibuf = (__half*)(ws + ((size_t)25 << 20));    // 16 MB [2048,4096]

    // fused prep + weight transpose-convert (coalesced reads AND writes)
    prep_conv_kernel<<<3136, 256, 0, stream>>>(inputs, state, W_r, W_u, W_d,
                                               fused, reset, WruT, WdT);

    // combined r+u GEMM with fused gate epilogue: [2048,1024] x [8192,1024]^T
    // 256^2 tile, 4-phase counted-vmcnt schedule, 512 thr (round-4 version).
    gemm_big<<<dim3(NRU2 / 256, B_SZ / 256), 512, 0, stream>>>(
        fused, WruT, b_r, b_u, state, reset, skibuf);

    // detect GEMM + fused final update: 256 blocks = full machine.
    gemm_detect<<<dim3(U_N / 128, B_SZ / 32), 256, 0, stream>>>(
        reset, WdT, b_d, skibuf, state, elapsed, out, out + (size_t)B_SZ * U_N);
}